// Round 4
// baseline (393.793 us; speedup 1.0000x reference)
//
#include <hip/hip_runtime.h>
#include <hip/hip_bf16.h>
#include <math.h>
#include <type_traits>

#define AS1 __attribute__((address_space(1)))
#define AS3 __attribute__((address_space(3)))

typedef __bf16  bf16x8 __attribute__((ext_vector_type(8)));
typedef float   f32x4  __attribute__((ext_vector_type(4)));
typedef float   f32x16 __attribute__((ext_vector_type(16)));
typedef __hip_bfloat16 bf16;

#define MFMA16x16x32 __builtin_amdgcn_mfma_f32_16x16x32_bf16
#define MFMA32x32x16 __builtin_amdgcn_mfma_f32_32x32x16_bf16

__device__ __forceinline__ void gload16(const void* g, void* l) {
  // async global->LDS, 16B per lane; LDS dest = wave-uniform base + lane*16
  __builtin_amdgcn_global_load_lds((const AS1 void*)g, (AS3 void*)l, 16, 0, 0);
}

__device__ __forceinline__ unsigned short bfbits(float v) {
  return __builtin_bit_cast(unsigned short, __float2bfloat16(v));
}

// ---------------------------------------------------------------- fused fp32 -> bf16 casts
struct CastArgs {
  const float4* src[6];
  ushort4* dst[6];
  unsigned bound[6];  // cumulative float4 counts
};

__global__ __launch_bounds__(256) void f2bf_multi(CastArgs a) {
  unsigned i = blockIdx.x * 256 + threadIdx.x;
  if (i >= a.bound[5]) return;
  unsigned lo = 0;
  int s = 0;
#pragma unroll
  for (int k = 0; k < 5; k++) {
    if (i >= a.bound[k]) { s = k + 1; lo = a.bound[k]; }
  }
  unsigned idx = i - lo;
  float4 v = a.src[s][idx];
  ushort4 o;
  o.x = bfbits(v.x); o.y = bfbits(v.y); o.z = bfbits(v.z); o.w = bfbits(v.w);
  a.dst[s][idx] = o;
}

// ---------------------------------------------------------------- GEMM  C = A * W^T
// A: (M,K) bf16, row stride lda.  W: (N,K) bf16 contiguous.  C: (M,N) OutT row-major.
template <typename OutT>
__global__ __launch_bounds__(256, 3) void gemm_bt(const bf16* __restrict__ A,
                                                  const bf16* __restrict__ W,
                                                  OutT* __restrict__ Cp,
                                                  int M, int N, int K, int lda) {
  __shared__ __align__(16) bf16 As[128 * 32];
  __shared__ __align__(16) bf16 Ws[128 * 32];
  const int t = threadIdx.x;
  const int w = t >> 6, lane = t & 63;
  const int quad = lane >> 4, l16 = lane & 15;
  const int wr = (w >> 1) * 64, wc = (w & 1) * 64;
  const size_t m0 = (size_t)blockIdx.x * 128;
  const size_t n0 = (size_t)blockIdx.y * 128;
  const int rowS = t >> 2;
  const int kch  = (t & 3) * 8;

  f32x4 acc[4][4];
#pragma unroll
  for (int i = 0; i < 4; i++)
#pragma unroll
    for (int j = 0; j < 4; j++) acc[i][j] = f32x4{0.f, 0.f, 0.f, 0.f};

  for (int k0 = 0; k0 < K; k0 += 32) {
    __syncthreads();
    gload16(A + (m0 + rowS) * (size_t)lda + k0 + kch,      (char*)As + w * 1024);
    gload16(A + (m0 + rowS + 64) * (size_t)lda + k0 + kch, (char*)As + 4096 + w * 1024);
    gload16(W + (n0 + rowS) * (size_t)K + k0 + kch,        (char*)Ws + w * 1024);
    gload16(W + (n0 + rowS + 64) * (size_t)K + k0 + kch,   (char*)Ws + 4096 + w * 1024);
    __syncthreads();

    bf16x8 af[4], bw[4];
#pragma unroll
    for (int i = 0; i < 4; i++)
      af[i] = *(const bf16x8*)(As + (wr + i * 16 + l16) * 32 + quad * 8);
#pragma unroll
    for (int j = 0; j < 4; j++)
      bw[j] = *(const bf16x8*)(Ws + (wc + j * 16 + l16) * 32 + quad * 8);
#pragma unroll
    for (int i = 0; i < 4; i++)
#pragma unroll
      for (int j = 0; j < 4; j++)
        acc[i][j] = MFMA16x16x32(af[i], bw[j], acc[i][j], 0, 0, 0);
  }

#pragma unroll
  for (int i = 0; i < 4; i++)
#pragma unroll
    for (int j = 0; j < 4; j++)
#pragma unroll
      for (int r = 0; r < 4; r++) {
        size_t row = m0 + wr + i * 16 + quad * 4 + r;
        size_t col = n0 + wc + j * 16 + l16;
        float v = acc[i][j][r];
        if constexpr (std::is_same<OutT, float>::value)
          Cp[row * N + col] = v;
        else
          Cp[row * N + col] = __float2bfloat16(v);
      }
}

// ---------------------------------------------------------------- kv_up GEMM with V-transpose epilogue
// A: (4096,512) stride 2048.  W: (4096,512).  K-halves -> kvraw (4096,4096);
// V-halves -> vT (B,H,128,T).  N-tile of 128 = exactly one half of one head.
__global__ __launch_bounds__(256, 3) void gemm_kvup(const bf16* __restrict__ A,
                                                    const bf16* __restrict__ W,
                                                    bf16* __restrict__ kvraw,
                                                    bf16* __restrict__ vT) {
  __shared__ __align__(16) bf16 As[128 * 32];
  __shared__ __align__(16) bf16 Ws[128 * 32];
  const int t = threadIdx.x;
  const int w = t >> 6, lane = t & 63;
  const int quad = lane >> 4, l16 = lane & 15;
  const int wr = (w >> 1) * 64, wc = (w & 1) * 64;
  const size_t m0 = (size_t)blockIdx.x * 128;
  const int n0 = (int)blockIdx.y * 128;
  const int rowS = t >> 2;
  const int kch  = (t & 3) * 8;
  const int K = 512, lda = 2048;

  f32x4 acc[4][4];
#pragma unroll
  for (int i = 0; i < 4; i++)
#pragma unroll
    for (int j = 0; j < 4; j++) acc[i][j] = f32x4{0.f, 0.f, 0.f, 0.f};

  for (int k0 = 0; k0 < K; k0 += 32) {
    __syncthreads();
    gload16(A + (m0 + rowS) * (size_t)lda + k0 + kch,        (char*)As + w * 1024);
    gload16(A + (m0 + rowS + 64) * (size_t)lda + k0 + kch,   (char*)As + 4096 + w * 1024);
    gload16(W + ((size_t)n0 + rowS) * K + k0 + kch,          (char*)Ws + w * 1024);
    gload16(W + ((size_t)n0 + rowS + 64) * K + k0 + kch,     (char*)Ws + 4096 + w * 1024);
    __syncthreads();

    bf16x8 af[4], bw[4];
#pragma unroll
    for (int i = 0; i < 4; i++)
      af[i] = *(const bf16x8*)(As + (wr + i * 16 + l16) * 32 + quad * 8);
#pragma unroll
    for (int j = 0; j < 4; j++)
      bw[j] = *(const bf16x8*)(Ws + (wc + j * 16 + l16) * 32 + quad * 8);
#pragma unroll
    for (int i = 0; i < 4; i++)
#pragma unroll
      for (int j = 0; j < 4; j++)
        acc[i][j] = MFMA16x16x32(af[i], bw[j], acc[i][j], 0, 0, 0);
  }

  if ((n0 & 128) == 0) {
    // K-half of a head: normal row-major store into kvraw
#pragma unroll
    for (int i = 0; i < 4; i++)
#pragma unroll
      for (int j = 0; j < 4; j++)
#pragma unroll
        for (int r = 0; r < 4; r++) {
          size_t row = m0 + wr + i * 16 + quad * 4 + r;
          size_t col = (size_t)n0 + wc + j * 16 + l16;
          kvraw[row * 4096 + col] = __float2bfloat16(acc[i][j][r]);
        }
  } else {
    // V-half: write transposed into vT[(b*16+h)*128 + d][t], 4 t-contiguous per store
    const int h = n0 >> 8;
#pragma unroll
    for (int i = 0; i < 4; i++) {
      size_t row = m0 + wr + i * 16 + quad * 4;  // +r, all same b
      int bb = (int)(row >> 11), tloc = (int)(row & 2047);
#pragma unroll
      for (int j = 0; j < 4; j++) {
        int d = wc + j * 16 + l16;
        ushort4 v4;
        v4.x = bfbits(acc[i][j][0]);
        v4.y = bfbits(acc[i][j][1]);
        v4.z = bfbits(acc[i][j][2]);
        v4.w = bfbits(acc[i][j][3]);
        *(ushort4*)(vT + ((size_t)(bb * 16 + h) * 128 + d) * 2048 + tloc) = v4;
      }
    }
  }
}

// ---------------------------------------------------------------- RoPE + RMSNorm
__global__ __launch_bounds__(256) void rope_rms(const bf16* __restrict__ qraw,
                                                const bf16* __restrict__ kvraw,
                                                const float* __restrict__ cosp,
                                                const float* __restrict__ sinp,
                                                bf16* __restrict__ qn,
                                                bf16* __restrict__ kn) {
  const int bt = blockIdx.x;
  const int w = threadIdx.x >> 6, lane = threadIdx.x & 63;
  const int h = blockIdx.y * 4 + w;
  const int tt = bt & 2047;  // T = 2048
  const float c = cosp[tt * 32 + (lane & 31)];
  const float s = sinp[tt * 32 + (lane & 31)];
  const float inv128 = 1.0f / 128.0f;
  const float eps = 1.1920929e-7f;

  // Q
  {
    const bf16* base = qraw + (size_t)bt * 2048 + h * 128;
    float a = (float)base[lane];
    float o = (float)base[64 + lane];
    float partner = __shfl_xor(o, 32);
    float orope = (lane < 32) ? (o * c + partner * s) : (o * c - partner * s);
    float ss = a * a + orope * orope;
#pragma unroll
    for (int off = 1; off < 64; off <<= 1) ss += __shfl_xor(ss, off);
    float rn = rsqrtf(ss * inv128 + eps);
    bf16* outp = qn + ((size_t)bt * 16 + h) * 128;
    outp[lane] = __float2bfloat16(a * rn);
    outp[64 + lane] = __float2bfloat16(orope * rn);
  }
  // K
  {
    const bf16* base = kvraw + (size_t)bt * 4096 + h * 256;
    float a = (float)base[lane];
    float o = (float)base[64 + lane];
    float partner = __shfl_xor(o, 32);
    float orope = (lane < 32) ? (o * c + partner * s) : (o * c - partner * s);
    float ss = a * a + orope * orope;
#pragma unroll
    for (int off = 1; off < 64; off <<= 1) ss += __shfl_xor(ss, off);
    float rn = rsqrtf(ss * inv128 + eps);
    bf16* outp = kn + ((size_t)bt * 16 + h) * 128;
    outp[lane] = __float2bfloat16(a * rn);
    outp[64 + lane] = __float2bfloat16(orope * rn);
  }
}

// ---------------------------------------------------------------- flash attention
// 64 q-rows/block, 2 waves x 32 rows (32x32x16 MFMA), 64-wide KV tiles.
// Fragment/swizzle math identical to R3 (correctness-verified); only the
// parallel decomposition changed: 1024 blocks, 40KB LDS -> 4 blocks/CU,
// xb bijection gives constant 66 tiles64 per CU.
__global__ __launch_bounds__(128, 2) void attn_kernel(const bf16* __restrict__ qn,
                                                      const bf16* __restrict__ kn,
                                                      const bf16* __restrict__ vT,
                                                      bf16* __restrict__ y) {
  __shared__ __align__(16) bf16 Ks[64 * 128];   // [s][k-chunks swizzled]
  __shared__ __align__(16) bf16 Vs[128 * 64];   // [d][s-chunks swizzled]
  __shared__ __align__(16) bf16 Ps[2][32 * 64]; // per-wave P, chunk-swizzled
  const int t = threadIdx.x, w = t >> 6, lane = t & 63;
  const int l32 = lane & 31, hl = lane >> 5;
  const int b = blockIdx.x >> 4, h = blockIdx.x & 15;
  const int yy = (int)blockIdx.y;
  const int y0 = yy & 7, k4 = yy >> 3;
  // residue-class-balanced bijection: CU's 4 blocks (y0, y0+8, y0+16, y0+24)
  // get xb {31-y0, y0, 23-y0, 8+y0}: constant sum 62 -> 66 tiles64/CU.
  int xb;
  if (k4 == 0) xb = 31 - y0;
  else if (k4 == 1) xb = y0;
  else if (k4 == 2) xb = 23 - y0;
  else xb = 8 + y0;
  const int q0 = xb * 64;
  const int T_ = 2048, H_ = 16;

  // Q frags: wave w owns q-rows q0+w*32+l32; k = ki*16 + hl*8 + j
  bf16x8 qf[8];
  {
    const bf16* qbase = qn + ((size_t)(b * T_ + q0 + w * 32 + l32) * H_ + h) * 128;
#pragma unroll
    for (int ki = 0; ki < 8; ki++)
      qf[ki] = *(const bf16x8*)(qbase + ki * 16 + hl * 8);
  }

  f32x16 yacc[4];
#pragma unroll
  for (int db = 0; db < 4; db++)
#pragma unroll
    for (int i = 0; i < 16; i++) yacc[db][i] = 0.f;
  float lrow[16];
#pragma unroll
  for (int r = 0; r < 16; r++) lrow[r] = 0.f;
  const float K1 = 0.08838834764831845f * 1.4426950408889634f;
  const float K2 = -12.0f * 1.4426950408889634f;
  const int ntiles = xb + 1;

  for (int it = 0; it < ntiles; ++it) {
    const int s0 = it * 64;
    __syncthreads();
    // stage K tile: 16 instrs (8/wave), instr i covers rows 4i..4i+3
#pragma unroll
    for (int is = 0; is < 8; ++is) {
      int i = is * 2 + w;
      int srow = i * 4 + (lane >> 4);
      int cg = (lane & 15) ^ (srow & 7);
      gload16(kn + ((size_t)(b * T_ + s0 + srow) * H_ + h) * 128 + cg * 8,
              (char*)Ks + i * 1024);
    }
    // stage V tile: 16 instrs (8/wave), instr i covers d-rows 8i..8i+7
#pragma unroll
    for (int is = 0; is < 8; ++is) {
      int i = is * 2 + w;
      int drow = i * 8 + (lane >> 3);
      int cg = (lane & 7) ^ (drow & 7);
      gload16(vT + ((size_t)(b * H_ + h) * 128 + drow) * T_ + s0 + cg * 8,
              (char*)Vs + i * 1024);
    }
    __syncthreads();

    // S = Q K^T : 2 col-blocks x 8 k-iters
    f32x16 sacc[2];
#pragma unroll
    for (int cb = 0; cb < 2; cb++)
#pragma unroll
      for (int i = 0; i < 16; i++) sacc[cb][i] = 0.f;
#pragma unroll
    for (int cb = 0; cb < 2; ++cb) {
      const int s = cb * 32 + l32;
#pragma unroll
      for (int ki = 0; ki < 8; ++ki) {
        int pos = (ki * 2 + hl) ^ (s & 7);
        bf16x8 kf = *(const bf16x8*)(Ks + s * 128 + pos * 8);
        sacc[cb] = MFMA32x32x16(qf[ki], kf, sacc[cb], 0, 0, 0);
      }
    }

    // fixed-max softmax + store P to per-wave LDS (chunk-swizzled)
    const bool diag = (it == xb);
#pragma unroll
    for (int cb = 0; cb < 2; ++cb) {
      const int sidx = cb * 32 + l32;
      const int sg = s0 + sidx;
#pragma unroll
      for (int r = 0; r < 16; ++r) {
        const int row = (r & 3) + 8 * (r >> 2) + 4 * hl;
        float e;
        if (diag && (sg > q0 + w * 32 + row))
          e = 0.0f;
        else
          e = exp2f(fmaf(sacc[cb][r], K1, K2));
        lrow[r] += e;
        Ps[w][row * 64 + (((sidx >> 3) ^ (row & 7)) << 3) + (sidx & 7)] =
            __float2bfloat16(e);
      }
    }
    __asm__ volatile("s_waitcnt lgkmcnt(0)" ::: "memory");

    // O += P V : A-frag from Ps (m=l32), B-frag from Vs (n=d)
#pragma unroll
    for (int ki = 0; ki < 4; ++ki) {
      int ppos = (ki * 2 + hl) ^ (l32 & 7);
      bf16x8 pf = *(const bf16x8*)(&Ps[w][l32 * 64 + ppos * 8]);
#pragma unroll
      for (int db = 0; db < 4; ++db) {
        int d = db * 32 + l32;
        int vpos = (ki * 2 + hl) ^ (d & 7);
        bf16x8 vf = *(const bf16x8*)(Vs + d * 64 + vpos * 8);
        yacc[db] = MFMA32x32x16(pf, vf, yacc[db], 0, 0, 0);
      }
    }
  }

  // epilogue: reduce l partials across 32 s-lanes (hl halves stay separate)
#pragma unroll
  for (int r = 0; r < 16; r++) {
#pragma unroll
    for (int off = 1; off < 32; off <<= 1) lrow[r] += __shfl_xor(lrow[r], off);
  }
#pragma unroll
  for (int r = 0; r < 16; r++) {
    const int row = (r & 3) + 8 * (r >> 2) + 4 * hl;
    float inv = 1.0f / lrow[r];
    size_t qrow = (size_t)(b * T_ + q0 + w * 32 + row);
    bf16* outp = y + qrow * 2048 + h * 128;
#pragma unroll
    for (int db = 0; db < 4; db++)
      outp[db * 32 + l32] = __float2bfloat16(yacc[db][r] * inv);
  }
}

// ---------------------------------------------------------------- launcher
extern "C" void kernel_launch(void* const* d_in, const int* in_sizes, int n_in,
                              void* d_out, int out_size, void* d_ws, size_t ws_size,
                              hipStream_t stream) {
  (void)in_sizes; (void)n_in; (void)out_size; (void)ws_size;
  const float* x    = (const float*)d_in[0];
  const float* cosp = (const float*)d_in[1];
  const float* sinp = (const float*)d_in[2];
  const float* wqd  = (const float*)d_in[3];
  const float* wqu  = (const float*)d_in[4];
  const float* wkvd = (const float*)d_in[5];
  const float* wkvu = (const float*)d_in[6];
  const float* wo   = (const float*)d_in[7];
  float* out = (float*)d_out;

  char* ws = (char*)d_ws;
  size_t off = 0;
  auto alloc = [&](size_t elems) { bf16* p = (bf16*)(ws + off); off += elems * 2; return p; };
  bf16* xb      = alloc((size_t)4096 * 2048);
  bf16* wqdB    = alloc((size_t)1536 * 2048);  // wqdB+wkvdB contiguous: fused (2048,2048) W
  bf16* wkvdB   = alloc((size_t)512 * 2048);
  bf16* wquB    = alloc((size_t)2048 * 1536);
  bf16* wkvuB   = alloc((size_t)4096 * 512);
  bf16* woB     = alloc((size_t)2048 * 2048);
  bf16* qkvdown = alloc((size_t)4096 * 2048);  // cols 0..1535 = qdown, 1536..2047 = kvdown
  bf16* qraw    = alloc((size_t)4096 * 2048);
  bf16* kvraw   = alloc((size_t)4096 * 4096);  // only K-halves written/used
  bf16* qnb     = alloc((size_t)4096 * 16 * 128);
  bf16* knb     = alloc((size_t)4096 * 16 * 128);
  bf16* vTb     = alloc((size_t)2 * 16 * 128 * 2048);
  bf16* yb      = alloc((size_t)4096 * 2048);

  // one fused cast launch for all six fp32->bf16 conversions
  CastArgs ca;
  const float* srcs[6] = {x, wqd, wkvd, wqu, wkvu, wo};
  bf16* dsts[6]        = {xb, wqdB, wkvdB, wquB, wkvuB, woB};
  size_t cnts[6] = {(size_t)4096 * 2048, (size_t)1536 * 2048, (size_t)512 * 2048,
                    (size_t)2048 * 1536, (size_t)4096 * 512,  (size_t)2048 * 2048};
  unsigned cum = 0;
  for (int i = 0; i < 6; i++) {
    ca.src[i] = (const float4*)srcs[i];
    ca.dst[i] = (ushort4*)dsts[i];
    cum += (unsigned)(cnts[i] / 4);
    ca.bound[i] = cum;
  }
  f2bf_multi<<<dim3((cum + 255) / 256), 256, 0, stream>>>(ca);

  // fused down-proj: (4096 x 2048) = x @ [wq_down; wkv_down]^T
  gemm_bt<bf16><<<dim3(32, 16), 256, 0, stream>>>(xb, wqdB, qkvdown, 4096, 2048, 2048, 2048);
  // q up-projection (strided A)
  gemm_bt<bf16><<<dim3(32, 16), 256, 0, stream>>>(qkvdown, wquB, qraw, 4096, 2048, 1536, 2048);
  // kv up-projection with fused V-transpose epilogue (replaces gemm + vtrans)
  gemm_kvup<<<dim3(32, 32), 256, 0, stream>>>(qkvdown + 1536, wkvuB, kvraw, vTb);
  rope_rms<<<dim3(4096, 4), 256, 0, stream>>>(qraw, kvraw, cosp, sinp, qnb, knb);
  attn_kernel<<<dim3(32, 32), 128, 0, stream>>>(qnb, knb, vTb, yb);
  gemm_bt<float><<<dim3(32, 16), 256, 0, stream>>>(yb, woB, out, 4096, 2048, 2048, 2048);
}

// Round 5
// 375.817 us; speedup vs baseline: 1.0478x; 1.0478x over previous
//
#include <hip/hip_runtime.h>
#include <hip/hip_bf16.h>
#include <math.h>
#include <type_traits>

#define AS1 __attribute__((address_space(1)))
#define AS3 __attribute__((address_space(3)))

typedef __bf16  bf16x8 __attribute__((ext_vector_type(8)));
typedef float   f32x4  __attribute__((ext_vector_type(4)));
typedef __hip_bfloat16 bf16;

#define MFMA16x16x32 __builtin_amdgcn_mfma_f32_16x16x32_bf16

__device__ __forceinline__ void gload16(const void* g, void* l) {
  // async global->LDS, 16B per lane; LDS dest = wave-uniform base + lane*16
  __builtin_amdgcn_global_load_lds((const AS1 void*)g, (AS3 void*)l, 16, 0, 0);
}

__device__ __forceinline__ unsigned short bfbits(float v) {
  return __builtin_bit_cast(unsigned short, __float2bfloat16(v));
}

// ---------------------------------------------------------------- fused fp32 -> bf16 casts
struct CastArgs {
  const float4* src[6];
  ushort4* dst[6];
  unsigned bound[6];  // cumulative float4 counts
};

__global__ __launch_bounds__(256) void f2bf_multi(CastArgs a) {
  unsigned i = blockIdx.x * 256 + threadIdx.x;
  if (i >= a.bound[5]) return;
  unsigned lo = 0;
  int s = 0;
#pragma unroll
  for (int k = 0; k < 5; k++) {
    if (i >= a.bound[k]) { s = k + 1; lo = a.bound[k]; }
  }
  unsigned idx = i - lo;
  float4 v = a.src[s][idx];
  ushort4 o;
  o.x = bfbits(v.x); o.y = bfbits(v.y); o.z = bfbits(v.z); o.w = bfbits(v.w);
  a.dst[s][idx] = o;
}

// ---------------------------------------------------------------- GEMM  C = A * W^T
// A: (M,K) bf16, row stride lda.  W: (N,K) bf16 contiguous.  C: (M,N) OutT row-major.
template <typename OutT>
__global__ __launch_bounds__(256, 3) void gemm_bt(const bf16* __restrict__ A,
                                                  const bf16* __restrict__ W,
                                                  OutT* __restrict__ Cp,
                                                  int M, int N, int K, int lda) {
  __shared__ __align__(16) bf16 As[128 * 32];
  __shared__ __align__(16) bf16 Ws[128 * 32];
  const int t = threadIdx.x;
  const int w = t >> 6, lane = t & 63;
  const int quad = lane >> 4, l16 = lane & 15;
  const int wr = (w >> 1) * 64, wc = (w & 1) * 64;
  const size_t m0 = (size_t)blockIdx.x * 128;
  const size_t n0 = (size_t)blockIdx.y * 128;
  const int rowS = t >> 2;
  const int kch  = (t & 3) * 8;

  f32x4 acc[4][4];
#pragma unroll
  for (int i = 0; i < 4; i++)
#pragma unroll
    for (int j = 0; j < 4; j++) acc[i][j] = f32x4{0.f, 0.f, 0.f, 0.f};

  for (int k0 = 0; k0 < K; k0 += 32) {
    __syncthreads();
    gload16(A + (m0 + rowS) * (size_t)lda + k0 + kch,      (char*)As + w * 1024);
    gload16(A + (m0 + rowS + 64) * (size_t)lda + k0 + kch, (char*)As + 4096 + w * 1024);
    gload16(W + (n0 + rowS) * (size_t)K + k0 + kch,        (char*)Ws + w * 1024);
    gload16(W + (n0 + rowS + 64) * (size_t)K + k0 + kch,   (char*)Ws + 4096 + w * 1024);
    __syncthreads();

    bf16x8 af[4], bw[4];
#pragma unroll
    for (int i = 0; i < 4; i++)
      af[i] = *(const bf16x8*)(As + (wr + i * 16 + l16) * 32 + quad * 8);
#pragma unroll
    for (int j = 0; j < 4; j++)
      bw[j] = *(const bf16x8*)(Ws + (wc + j * 16 + l16) * 32 + quad * 8);
#pragma unroll
    for (int i = 0; i < 4; i++)
#pragma unroll
      for (int j = 0; j < 4; j++)
        acc[i][j] = MFMA16x16x32(af[i], bw[j], acc[i][j], 0, 0, 0);
  }

#pragma unroll
  for (int i = 0; i < 4; i++)
#pragma unroll
    for (int j = 0; j < 4; j++)
#pragma unroll
      for (int r = 0; r < 4; r++) {
        size_t row = m0 + wr + i * 16 + quad * 4 + r;
        size_t col = n0 + wc + j * 16 + l16;
        float v = acc[i][j][r];
        if constexpr (std::is_same<OutT, float>::value)
          Cp[row * N + col] = v;
        else
          Cp[row * N + col] = __float2bfloat16(v);
      }
}

// ---------------------------------------------------------------- kv_up GEMM with V-transpose epilogue
// A: (4096,512) stride 2048.  W: (4096,512).  K-halves -> kvraw (4096,4096);
// V-halves -> vT (B,H,128,T).  N-tile of 128 = exactly one half of one head.
__global__ __launch_bounds__(256, 3) void gemm_kvup(const bf16* __restrict__ A,
                                                    const bf16* __restrict__ W,
                                                    bf16* __restrict__ kvraw,
                                                    bf16* __restrict__ vT) {
  __shared__ __align__(16) bf16 As[128 * 32];
  __shared__ __align__(16) bf16 Ws[128 * 32];
  const int t = threadIdx.x;
  const int w = t >> 6, lane = t & 63;
  const int quad = lane >> 4, l16 = lane & 15;
  const int wr = (w >> 1) * 64, wc = (w & 1) * 64;
  const size_t m0 = (size_t)blockIdx.x * 128;
  const int n0 = (int)blockIdx.y * 128;
  const int rowS = t >> 2;
  const int kch  = (t & 3) * 8;
  const int K = 512, lda = 2048;

  f32x4 acc[4][4];
#pragma unroll
  for (int i = 0; i < 4; i++)
#pragma unroll
    for (int j = 0; j < 4; j++) acc[i][j] = f32x4{0.f, 0.f, 0.f, 0.f};

  for (int k0 = 0; k0 < K; k0 += 32) {
    __syncthreads();
    gload16(A + (m0 + rowS) * (size_t)lda + k0 + kch,        (char*)As + w * 1024);
    gload16(A + (m0 + rowS + 64) * (size_t)lda + k0 + kch,   (char*)As + 4096 + w * 1024);
    gload16(W + ((size_t)n0 + rowS) * K + k0 + kch,          (char*)Ws + w * 1024);
    gload16(W + ((size_t)n0 + rowS + 64) * K + k0 + kch,     (char*)Ws + 4096 + w * 1024);
    __syncthreads();

    bf16x8 af[4], bw[4];
#pragma unroll
    for (int i = 0; i < 4; i++)
      af[i] = *(const bf16x8*)(As + (wr + i * 16 + l16) * 32 + quad * 8);
#pragma unroll
    for (int j = 0; j < 4; j++)
      bw[j] = *(const bf16x8*)(Ws + (wc + j * 16 + l16) * 32 + quad * 8);
#pragma unroll
    for (int i = 0; i < 4; i++)
#pragma unroll
      for (int j = 0; j < 4; j++)
        acc[i][j] = MFMA16x16x32(af[i], bw[j], acc[i][j], 0, 0, 0);
  }

  if ((n0 & 128) == 0) {
    // K-half of a head: normal row-major store into kvraw
#pragma unroll
    for (int i = 0; i < 4; i++)
#pragma unroll
      for (int j = 0; j < 4; j++)
#pragma unroll
        for (int r = 0; r < 4; r++) {
          size_t row = m0 + wr + i * 16 + quad * 4 + r;
          size_t col = (size_t)n0 + wc + j * 16 + l16;
          kvraw[row * 4096 + col] = __float2bfloat16(acc[i][j][r]);
        }
  } else {
    // V-half: write transposed into vT[(b*16+h)*128 + d][t], 4 t-contiguous per store
    const int h = n0 >> 8;
#pragma unroll
    for (int i = 0; i < 4; i++) {
      size_t row = m0 + wr + i * 16 + quad * 4;  // +r, all same b
      int bb = (int)(row >> 11), tloc = (int)(row & 2047);
#pragma unroll
      for (int j = 0; j < 4; j++) {
        int d = wc + j * 16 + l16;
        ushort4 v4;
        v4.x = bfbits(acc[i][j][0]);
        v4.y = bfbits(acc[i][j][1]);
        v4.z = bfbits(acc[i][j][2]);
        v4.w = bfbits(acc[i][j][3]);
        *(ushort4*)(vT + ((size_t)(bb * 16 + h) * 128 + d) * 2048 + tloc) = v4;
      }
    }
  }
}

// ---------------------------------------------------------------- RoPE + RMSNorm
__global__ __launch_bounds__(256) void rope_rms(const bf16* __restrict__ qraw,
                                                const bf16* __restrict__ kvraw,
                                                const float* __restrict__ cosp,
                                                const float* __restrict__ sinp,
                                                bf16* __restrict__ qn,
                                                bf16* __restrict__ kn) {
  const int bt = blockIdx.x;
  const int w = threadIdx.x >> 6, lane = threadIdx.x & 63;
  const int h = blockIdx.y * 4 + w;
  const int tt = bt & 2047;  // T = 2048
  const float c = cosp[tt * 32 + (lane & 31)];
  const float s = sinp[tt * 32 + (lane & 31)];
  const float inv128 = 1.0f / 128.0f;
  const float eps = 1.1920929e-7f;

  // Q
  {
    const bf16* base = qraw + (size_t)bt * 2048 + h * 128;
    float a = (float)base[lane];
    float o = (float)base[64 + lane];
    float partner = __shfl_xor(o, 32);
    float orope = (lane < 32) ? (o * c + partner * s) : (o * c - partner * s);
    float ss = a * a + orope * orope;
#pragma unroll
    for (int off = 1; off < 64; off <<= 1) ss += __shfl_xor(ss, off);
    float rn = rsqrtf(ss * inv128 + eps);
    bf16* outp = qn + ((size_t)bt * 16 + h) * 128;
    outp[lane] = __float2bfloat16(a * rn);
    outp[64 + lane] = __float2bfloat16(orope * rn);
  }
  // K
  {
    const bf16* base = kvraw + (size_t)bt * 4096 + h * 256;
    float a = (float)base[lane];
    float o = (float)base[64 + lane];
    float partner = __shfl_xor(o, 32);
    float orope = (lane < 32) ? (o * c + partner * s) : (o * c - partner * s);
    float ss = a * a + orope * orope;
#pragma unroll
    for (int off = 1; off < 64; off <<= 1) ss += __shfl_xor(ss, off);
    float rn = rsqrtf(ss * inv128 + eps);
    bf16* outp = kn + ((size_t)bt * 16 + h) * 128;
    outp[lane] = __float2bfloat16(a * rn);
    outp[64 + lane] = __float2bfloat16(orope * rn);
  }
}

// ---------------------------------------------------------------- flash attention
// R2 structure (empirically best): 64 q-rows/block, 4 waves x 16 rows,
// 16x16x32 MFMA, 64-wide KV tiles, fixed-max softmax.
// Changes vs R2: Ps stride 72->64 w/ XOR-chunk swizzle -> LDS 40960 B
// (4 blocks/CU); __launch_bounds__(256,4); exact-balance xb bijection
// (co-resident residue set {y0,y0+8,y0+16,y0+24} -> constant 66 tiles/CU).
__global__ __launch_bounds__(256, 4) void attn_kernel(const bf16* __restrict__ qn,
                                                      const bf16* __restrict__ kn,
                                                      const bf16* __restrict__ vT,
                                                      bf16* __restrict__ y) {
  __shared__ __align__(16) bf16 Ks[64 * 128];    // [s][d-chunks swizzled]  16 KB
  __shared__ __align__(16) bf16 Vs[128 * 64];    // [d][s-chunks swizzled]  16 KB
  __shared__ __align__(16) bf16 Ps[4][16 * 64];  // per-wave P, swizzled     8 KB
  const int t = threadIdx.x, w = t >> 6, lane = t & 63;
  const int quad = lane >> 4, l16 = lane & 15;
  const int b = blockIdx.x >> 4, h = blockIdx.x & 15;
  const int yy = (int)blockIdx.y;
  const int y0 = yy & 7, k4 = yy >> 3;
  int xb;
  if (k4 == 0) xb = 31 - y0;
  else if (k4 == 1) xb = y0;
  else if (k4 == 2) xb = 23 - y0;
  else xb = 8 + y0;
  const int q0 = xb * 64;
  const int T_ = 2048, H_ = 16;

  bf16x8 qf[4];
  {
    const bf16* qbase = qn + ((size_t)(b * T_ + q0 + w * 16 + l16) * H_ + h) * 128;
#pragma unroll
    for (int ks = 0; ks < 4; ks++) qf[ks] = *(const bf16x8*)(qbase + ks * 32 + quad * 8);
  }
  f32x4 yacc[8];
#pragma unroll
  for (int i = 0; i < 8; i++) yacc[i] = f32x4{0.f, 0.f, 0.f, 0.f};
  float lrow[4] = {0.f, 0.f, 0.f, 0.f};
  // p = exp2(sacc * K1 + K2) = e^(sacc/sqrt(128) - 12);  |q.k|/sqrt(128) <= sqrt(128) < 12
  const float K1 = 0.08838834764831845f * 1.4426950408889634f;
  const float K2 = -12.0f * 1.4426950408889634f;
  const int ntiles = xb + 1;

  for (int it = 0; it < ntiles; ++it) {
    const int s0 = it * 64;
    __syncthreads();
    // stage K tile (rows 256B = 16 chunks, swizzle c^=(s&7))
#pragma unroll
    for (int is = 0; is < 4; ++is) {
      int srow = is * 16 + w * 4 + quad;
      int cg = l16 ^ (srow & 7);
      gload16(kn + ((size_t)(b * T_ + s0 + srow) * H_ + h) * 128 + cg * 8,
              (char*)Ks + is * 4096 + w * 1024);
    }
    // stage V tile (rows 128B = 8 chunks, swizzle c^=(d&7))
#pragma unroll
    for (int is = 0; is < 4; ++is) {
      int drow = is * 32 + w * 8 + (lane >> 3);
      int cg = (lane & 7) ^ (drow & 7);
      gload16(vT + ((size_t)(b * H_ + h) * 128 + drow) * T_ + s0 + cg * 8,
              (char*)Vs + is * 4096 + w * 1024);
    }
    __syncthreads();

    // S = Q K^T
    f32x4 sacc[4];
#pragma unroll
    for (int cg = 0; cg < 4; cg++) sacc[cg] = f32x4{0.f, 0.f, 0.f, 0.f};
#pragma unroll
    for (int cg = 0; cg < 4; ++cg) {
      const int srow = cg * 16 + l16;
#pragma unroll
      for (int ks = 0; ks < 4; ++ks) {
        int pos = (ks * 4 + quad) ^ (srow & 7);
        bf16x8 kf = *(const bf16x8*)(Ks + srow * 128 + pos * 8);
        sacc[cg] = MFMA16x16x32(qf[ks], kf, sacc[cg], 0, 0, 0);
      }
    }

    // fixed-max softmax: p = exp2(s*K1 + K2); per-lane partial l
    const bool diag = (it == xb);
    float p[4][4];
#pragma unroll
    for (int cg = 0; cg < 4; ++cg)
#pragma unroll
      for (int r = 0; r < 4; ++r) {
        float e;
        if (diag && (cg * 16 + l16 > w * 16 + quad * 4 + r))
          e = 0.0f;
        else
          e = exp2f(fmaf(sacc[cg][r], K1, K2));
        p[cg][r] = e;
        lrow[r] += e;
      }

    // P: C-layout -> LDS (stride 64, chunk-XOR swizzle) -> A-layout
#pragma unroll
    for (int cg = 0; cg < 4; cg++)
#pragma unroll
      for (int r = 0; r < 4; r++) {
        const int row = quad * 4 + r;
        const int col = cg * 16 + l16;
        Ps[w][row * 64 + (((col >> 3) ^ (row & 7)) << 3) + (col & 7)] =
            __float2bfloat16(p[cg][r]);
      }
    __asm__ volatile("s_waitcnt lgkmcnt(0)" ::: "memory");

    bf16x8 pf[2];
#pragma unroll
    for (int k2 = 0; k2 < 2; k2++)
      pf[k2] = *(const bf16x8*)(&Ps[w][l16 * 64 + (((k2 * 4 + quad) ^ (l16 & 7)) << 3)]);
#pragma unroll
    for (int dg = 0; dg < 8; dg++) {
      const int drow = dg * 16 + l16;
#pragma unroll
      for (int k2 = 0; k2 < 2; k2++) {
        int pos = (k2 * 4 + quad) ^ (drow & 7);
        bf16x8 vf = *(const bf16x8*)(Vs + drow * 64 + pos * 8);
        yacc[dg] = MFMA16x16x32(pf[k2], vf, yacc[dg], 0, 0, 0);
      }
    }
  }

  // epilogue: reduce per-lane l partials across the 16 cols once, then scale
#pragma unroll
  for (int off = 1; off < 16; off <<= 1)
#pragma unroll
    for (int r = 0; r < 4; r++) lrow[r] += __shfl_xor(lrow[r], off);
#pragma unroll
  for (int r = 0; r < 4; r++) {
    float inv = 1.0f / lrow[r];
    size_t qrow = (size_t)(b * T_ + q0 + w * 16 + quad * 4 + r);
    bf16* outp = y + qrow * 2048 + h * 128;
#pragma unroll
    for (int dg = 0; dg < 8; dg++)
      outp[dg * 16 + l16] = __float2bfloat16(yacc[dg][r] * inv);
  }
}

// ---------------------------------------------------------------- launcher
extern "C" void kernel_launch(void* const* d_in, const int* in_sizes, int n_in,
                              void* d_out, int out_size, void* d_ws, size_t ws_size,
                              hipStream_t stream) {
  (void)in_sizes; (void)n_in; (void)out_size; (void)ws_size;
  const float* x    = (const float*)d_in[0];
  const float* cosp = (const float*)d_in[1];
  const float* sinp = (const float*)d_in[2];
  const float* wqd  = (const float*)d_in[3];
  const float* wqu  = (const float*)d_in[4];
  const float* wkvd = (const float*)d_in[5];
  const float* wkvu = (const float*)d_in[6];
  const float* wo   = (const float*)d_in[7];
  float* out = (float*)d_out;

  char* ws = (char*)d_ws;
  size_t off = 0;
  auto alloc = [&](size_t elems) { bf16* p = (bf16*)(ws + off); off += elems * 2; return p; };
  bf16* xb      = alloc((size_t)4096 * 2048);
  bf16* wqdB    = alloc((size_t)1536 * 2048);  // wqdB+wkvdB contiguous: fused (2048,2048) W
  bf16* wkvdB   = alloc((size_t)512 * 2048);
  bf16* wquB    = alloc((size_t)2048 * 1536);
  bf16* wkvuB   = alloc((size_t)4096 * 512);
  bf16* woB     = alloc((size_t)2048 * 2048);
  bf16* qkvdown = alloc((size_t)4096 * 2048);  // cols 0..1535 = qdown, 1536..2047 = kvdown
  bf16* qraw    = alloc((size_t)4096 * 2048);
  bf16* kvraw   = alloc((size_t)4096 * 4096);  // only K-halves written/used
  bf16* qnb     = alloc((size_t)4096 * 16 * 128);
  bf16* knb     = alloc((size_t)4096 * 16 * 128);
  bf16* vTb     = alloc((size_t)2 * 16 * 128 * 2048);
  bf16* yb      = alloc((size_t)4096 * 2048);

  // one fused cast launch for all six fp32->bf16 conversions
  CastArgs ca;
  const float* srcs[6] = {x, wqd, wkvd, wqu, wkvu, wo};
  bf16* dsts[6]        = {xb, wqdB, wkvdB, wquB, wkvuB, woB};
  size_t cnts[6] = {(size_t)4096 * 2048, (size_t)1536 * 2048, (size_t)512 * 2048,
                    (size_t)2048 * 1536, (size_t)4096 * 512,  (size_t)2048 * 2048};
  unsigned cum = 0;
  for (int i = 0; i < 6; i++) {
    ca.src[i] = (const float4*)srcs[i];
    ca.dst[i] = (ushort4*)dsts[i];
    cum += (unsigned)(cnts[i] / 4);
    ca.bound[i] = cum;
  }
  f2bf_multi<<<dim3((cum + 255) / 256), 256, 0, stream>>>(ca);

  // fused down-proj: (4096 x 2048) = x @ [wq_down; wkv_down]^T
  gemm_bt<bf16><<<dim3(32, 16), 256, 0, stream>>>(xb, wqdB, qkvdown, 4096, 2048, 2048, 2048);
  // q up-projection (strided A)
  gemm_bt<bf16><<<dim3(32, 16), 256, 0, stream>>>(qkvdown, wquB, qraw, 4096, 2048, 1536, 2048);
  // kv up-projection with fused V-transpose epilogue
  gemm_kvup<<<dim3(32, 32), 256, 0, stream>>>(qkvdown + 1536, wkvuB, kvraw, vTb);
  rope_rms<<<dim3(4096, 4), 256, 0, stream>>>(qraw, kvraw, cosp, sinp, qnb, knb);
  attn_kernel<<<dim3(32, 32), 256, 0, stream>>>(qnb, knb, vTb, yb);
  gemm_bt<float><<<dim3(32, 16), 256, 0, stream>>>(yb, woB, out, 4096, 2048, 2048, 2048);
}